// Round 18
// baseline (771.880 us; speedup 1.0000x reference)
//
#include <hip/hip_runtime.h>

typedef unsigned int uint;
typedef unsigned short ushort;
typedef _Float16 f16_t;
typedef f16_t f16x8 __attribute__((ext_vector_type(8)));
typedef ushort ushort8 __attribute__((ext_vector_type(8)));
typedef float f32x4 __attribute__((ext_vector_type(4)));

#define NN 200000
#define EE 600000
#define LL 5
#define GG 2000
#define SCAN_NB 782  // ceil(NN/256)

__device__ __forceinline__ ushort f2h(float f) {
  f16_t h = (f16_t)f;
  return __builtin_bit_cast(ushort, h);
}
__device__ __forceinline__ float h2f(ushort u) {
  return (float)__builtin_bit_cast(f16_t, u);
}
__device__ __forceinline__ float hlo(uint u) { return h2f((ushort)(u & 0xFFFFu)); }
__device__ __forceinline__ float hhi(uint u) { return h2f((ushort)(u >> 16)); }
__device__ __forceinline__ f16x8 ld8h(const uint4* p, int idx) {
  uint4 u = p[idx];
  return __builtin_bit_cast(f16x8, u);
}
// h = relu(z*sc+sh) in packed fp16 (v_pk_fma_f16 + v_pk_max_f16)
__device__ __forceinline__ f16x8 bnrelu8(f16x8 u, f16x8 sc, f16x8 sh) {
  f16x8 r = u * sc + sh;
#pragma unroll
  for (int j = 0; j < 8; ++j) r[j] = r[j] > (f16_t)0.f ? r[j] : (f16_t)0.f;
  return r;
}

// general (deg>16) sequential chain — rare fallback
__device__ __forceinline__ void chain_general(f16x8& acc, int s, int e, int sub, int ln16,
                                              const uint4* h4, const uint4* atomH,
                                              const uint4* combH,
                                              const int* __restrict__ eslot, f16x8 scv,
                                              f16x8 shv, int layer) {
  for (int base = s; base < e; base += 16) {
    int m = e - base;
    if (m > 16) m = 16;
    int slot = (ln16 < m) ? eslot[base + ln16] : 0;
    for (int j = 0; j < m; ++j) {
      int sl = __shfl(slot, sub * 16 + j, 64);
      f16x8 p;
      if (layer == 0)
        p = ld8h(atomH, ((sl >> 22) & 15) * 16 + ln16);
      else
        p = bnrelu8(ld8h(h4, (size_t)(sl & 0x3FFFF) * 16 + ln16), scv, shv);
      acc += p + ld8h(combH, ((sl >> 18) & 15) * 16 + ln16);
    }
  }
}

// ---------------- merged setup: weight swizzle + fp16 tables + xcode + outinit ------
__global__ void k_setup(const float* __restrict__ W1, const float* __restrict__ W2,
                        ushort* __restrict__ w1s, ushort* __restrict__ w2s,
                        const float* __restrict__ ee1, const float* __restrict__ ee2,
                        const float* __restrict__ at1, const float* __restrict__ at2,
                        ushort* __restrict__ tabh, const int* __restrict__ xidx,
                        int* __restrict__ xcode, float* __restrict__ out,
                        const float* __restrict__ bp) {
  int i = blockIdx.x * 256 + threadIdx.x;
  if (i < 40960) {  // weight swizzle, B-frag 16x16x32 order
    int lane = i & 63;
    int f = i >> 6;
    bool isW2 = false;
    if (f >= 320) { f -= 320; isW2 = true; }
    int l = f >> 6, rem = f & 63;
    ushort8 o;
    if (!isW2) {
      int kt = rem >> 4, nt = rem & 15;
      int n = nt * 16 + (lane & 15);
      int kbase = kt * 32 + (lane >> 4) * 8;
#pragma unroll
      for (int j = 0; j < 8; ++j) o[j] = f2h(W1[l * 32768 + (kbase + j) * 256 + n]);
      *(ushort8*)(w1s + f * 512 + lane * 8) = o;
    } else {
      int kt = rem >> 3, nt = rem & 7;
      int n = nt * 16 + (lane & 15);
      int kbase = kt * 32 + (lane >> 4) * 8;
#pragma unroll
      for (int j = 0; j < 8; ++j) o[j] = f2h(W2[l * 32768 + (kbase + j) * 128 + n]);
      *(ushort8*)(w2s + f * 512 + lane * 8) = o;
    }
  }
  if (i < 5760) {  // comb (packed fp16)
    int l = i / 1152, rem = i % 1152;
    int ab = rem >> 7, c = rem & 127;
    int a = ab / 3, b = ab - a * 3;
    tabh[i] = f2h(ee1[(l * 6 + a) * 128 + c] + ee2[(l * 3 + b) * 128 + c]);
  } else if (i < 6400) {  // selfv
    int j = i - 5760;
    int l = j >> 7, c = j & 127;
    tabh[i] = f2h(ee1[(l * 6 + 4) * 128 + c] + ee2[(l * 3 + 0) * 128 + c]);
  } else if (i < 7552) {  // atomc
    int j = i - 6400;
    int ab = j >> 7, c = j & 127;
    int a = ab / 3, b = ab - a * 3;
    tabh[i] = f2h(at1[a * 128 + c] + at2[b * 128 + c]);
  }
  if (i < NN) xcode[i] = xidx[2 * i] * 3 + xidx[2 * i + 1];
  if (i < GG) out[i] = bp[0];
}

// ---------------- CSR build (dst is fixed across layers) ----------------
__global__ void k_count(const int* __restrict__ ei, int* __restrict__ counts) {
  int e = blockIdx.x * 256 + threadIdx.x;
  if (e < EE) atomicAdd(&counts[ei[EE + e]], 1);
}

__global__ void k_scanA(const int* __restrict__ counts, int* __restrict__ rowptr,
                        int* __restrict__ bsums) {
  __shared__ int sd[256];
  int tid = threadIdx.x;
  int g = blockIdx.x * 256 + tid;
  int v = (g < NN) ? counts[g] : 0;
  sd[tid] = v;
  __syncthreads();
  for (int o = 1; o < 256; o <<= 1) {
    int t = (tid >= o) ? sd[tid - o] : 0;
    __syncthreads();
    sd[tid] += t;
    __syncthreads();
  }
  if (g < NN) rowptr[g] = sd[tid] - v;
  if (tid == 255) bsums[blockIdx.x] = sd[tid];
}

__global__ void k_scanB(int* __restrict__ bsums) {
  __shared__ int sd[1024];
  int tid = threadIdx.x;
  int v = (tid < SCAN_NB) ? bsums[tid] : 0;
  sd[tid] = v;
  __syncthreads();
  for (int o = 1; o < 1024; o <<= 1) {
    int t = (tid >= o) ? sd[tid - o] : 0;
    __syncthreads();
    sd[tid] += t;
    __syncthreads();
  }
  if (tid < SCAN_NB) bsums[tid] = sd[tid] - v;
}

__global__ void k_scanC(int* __restrict__ rowptr, const int* __restrict__ bsums) {
  int g = blockIdx.x * 256 + threadIdx.x;
  if (g < NN) rowptr[g] += bsums[blockIdx.x];
  if (g == 0) rowptr[NN] = EE;
}

// pack src (18b) | a9 (4b) | xcode_src (4b)
__global__ void k_fill(const int* __restrict__ ei, const int* __restrict__ ea,
                       const int* __restrict__ xcode, int* __restrict__ cursor,
                       int* __restrict__ eslot) {
  int e = blockIdx.x * 256 + threadIdx.x;
  if (e < EE) {
    int dst = ei[EE + e];
    int src = ei[e];
    int a9 = ea[2 * e] * 3 + ea[2 * e + 1];
    int sc = xcode[src];
    int pos = atomicAdd(&cursor[dst], 1);
    eslot[pos] = src | (a9 << 18) | (sc << 22);
  }
}

// ---------------- fused layer: dual-chain packed-fp16 gather, fp16 MLP, BN stats ----
// Each 16-lane sub-group owns TWO nodes (nA, nB) and walks their edge chains
// INTERLEAVED in one loop: 2 independent z-row loads in flight per sub-group
// (8/wave) and the serial chain wall ~halves vs sequential grp0-then-grp1.
// Off-chain iterations add a masked +0 (cndmask, branch-free). Rare deg>16
// falls back to the sequential chunked path. Accumulation order per node
// unchanged -> numerics identical. No fences (r16 lesson).
__global__ __launch_bounds__(256, 5) void k_layer(
    const ushort* __restrict__ zin, ushort* __restrict__ zout,
    const int* __restrict__ xcode, const ushort* __restrict__ tabh,
    const float* __restrict__ bnscale, const float* __restrict__ bnshift,
    const int* __restrict__ rowptr, const int* __restrict__ eslot,
    const ushort* __restrict__ w1s, const ushort* __restrict__ w2s,
    const float* __restrict__ b1, const float* __restrict__ b2,
    float* __restrict__ stats, int layer) {
  __shared__ __align__(16) ushort BUF[32 * 264];  // 16,896 B union
  ushort* AGG = BUF;   // 32 x 136 view (gather out / stage-1 in)
  ushort* T1 = BUF;    // 32 x 264 view (stage-1 out / stage-2 in)
  ushort* ldsZ = BUF;  // 32 x 136 view (stage-2 out / store staging)
  const int tid = threadIdx.x;
  const int w = tid >> 6, lane = tid & 63;
  const int ln16 = lane & 15, sub = lane >> 4;
  const int row0 = blockIdx.x * 32;

  // ---- gather phase: packed fp16, BN affine inlined, dual interleaved chains ----
  const uint4* combH = (const uint4*)(tabh + (size_t)layer * 1152);
  const uint4* atomH = (const uint4*)(tabh + 6400);
  const uint4* selfH = (const uint4*)(tabh + 5760 + layer * 128);
  const uint4* h4 = (const uint4*)zin;
  f16x8 sf = ld8h(selfH, ln16);
  f16x8 scv = {}, shv = {};
  if (layer > 0) {
    const float* sp = bnscale + (layer - 1) * 128 + ln16 * 8;
    const float* hp = bnshift + (layer - 1) * 128 + ln16 * 8;
#pragma unroll
    for (int j = 0; j < 8; ++j) {
      scv[j] = (f16_t)sp[j];
      shv[j] = (f16_t)hp[j];
    }
  }

  {
    const int nA = row0 + w * 8 + sub;
    const int nB = row0 + w * 8 + 4 + sub;
    const int sA = rowptr[nA], eA = rowptr[nA + 1];
    const int sB = rowptr[nB], eB = rowptr[nB + 1];
    const int mA = eA - sA, mB = eB - sB;
    f16x8 accA, accB;
    if (layer == 0) {
      accA = ld8h(atomH, xcode[nA] * 16 + ln16) + sf;
      accB = ld8h(atomH, xcode[nB] * 16 + ln16) + sf;
    } else {
      accA = bnrelu8(ld8h(h4, (size_t)nA * 16 + ln16), scv, shv) + sf;
      accB = bnrelu8(ld8h(h4, (size_t)nB * 16 + ln16), scv, shv) + sf;
    }
    if (mA <= 16 && mB <= 16) {  // fast path (P(deg>16) ~ 1e-8 at mean deg 3)
      int slotA = (ln16 < mA) ? eslot[sA + ln16] : 0;
      int slotB = (ln16 < mB) ? eslot[sB + ln16] : 0;
      int mx = mA > mB ? mA : mB;
      const uint4 zero4 = {0u, 0u, 0u, 0u};
      for (int j = 0; j < mx; ++j) {
        int slA = __shfl(slotA, sub * 16 + j, 64);
        int slB = __shfl(slotB, sub * 16 + j, 64);
        f16x8 pA, pB;
        if (layer == 0) {
          pA = ld8h(atomH, ((slA >> 22) & 15) * 16 + ln16);
          pB = ld8h(atomH, ((slB >> 22) & 15) * 16 + ln16);
        } else {
          pA = bnrelu8(ld8h(h4, (size_t)(slA & 0x3FFFF) * 16 + ln16), scv, shv);
          pB = bnrelu8(ld8h(h4, (size_t)(slB & 0x3FFFF) * 16 + ln16), scv, shv);
        }
        f16x8 cA = ld8h(combH, ((slA >> 18) & 15) * 16 + ln16);
        f16x8 cB = ld8h(combH, ((slB >> 18) & 15) * 16 + ln16);
        uint4 tA = __builtin_bit_cast(uint4, pA + cA);
        uint4 tB = __builtin_bit_cast(uint4, pB + cB);
        tA = (j < mA) ? tA : zero4;  // masked +0 for off-chain iterations
        tB = (j < mB) ? tB : zero4;
        accA += __builtin_bit_cast(f16x8, tA);
        accB += __builtin_bit_cast(f16x8, tB);
      }
    } else {  // general chunked path, sequential
      chain_general(accA, sA, eA, sub, ln16, h4, atomH, combH, eslot, scv, shv, layer);
      chain_general(accB, sB, eB, sub, ln16, h4, atomH, combH, eslot, scv, shv, layer);
    }
    *(uint4*)&AGG[(w * 8 + sub) * 136 + ln16 * 8] = __builtin_bit_cast(uint4, accA);
    *(uint4*)&AGG[(w * 8 + 4 + sub) * 136 + ln16 * 8] = __builtin_bit_cast(uint4, accB);
  }
  __syncthreads();

  // ---- MLP stage 1: acc = AGG @ W1, M=32, fp16; nt in pairs (smaller live set) ----
  const int lm = ln16, q = sub;
  f32x4 acc[2][4] = {};
  const ushort* w1b = w1s + layer * 64 * 512;
#pragma unroll
  for (int kt = 0; kt < 4; ++kt) {
    f16x8 af[2];
#pragma unroll
    for (int mt = 0; mt < 2; ++mt) {
      const ushort* p = AGG + (mt * 16 + lm) * 136 + kt * 32 + q * 8;
      af[mt] = __builtin_bit_cast(f16x8, *(const ushort8*)p);
    }
#pragma unroll
    for (int np = 0; np < 2; ++np) {
      f16x8 bf[2];
#pragma unroll
      for (int ni = 0; ni < 2; ++ni) {
        const ushort* p = w1b + (kt * 16 + w * 4 + np * 2 + ni) * 512 + lane * 8;
        bf[ni] = __builtin_bit_cast(f16x8, *(const ushort8*)p);
      }
#pragma unroll
      for (int mt = 0; mt < 2; ++mt)
#pragma unroll
        for (int ni = 0; ni < 2; ++ni)
          acc[mt][np * 2 + ni] = __builtin_amdgcn_mfma_f32_16x16x32_f16(
              af[mt], bf[ni], acc[mt][np * 2 + ni], 0, 0, 0);
    }
  }
  __syncthreads();  // AGG dead; T1 may now overwrite the union buffer
#pragma unroll
  for (int nt = 0; nt < 4; ++nt) {
    int n = w * 64 + nt * 16 + lm;
    float bias = b1[layer * 256 + n];
#pragma unroll
    for (int mt = 0; mt < 2; ++mt)
#pragma unroll
      for (int r = 0; r < 4; ++r) {
        float v = fmaxf(acc[mt][nt][r] + bias, 0.0f);
        T1[(mt * 16 + q * 4 + r) * 264 + n] = f2h(v);
      }
  }
  __syncthreads();

  // ---- MLP stage 2: z = T1 @ W2 + b2, + BN stats epilogue ----
  f32x4 acc2[2][2] = {};
  const ushort* w2b = w2s + layer * 64 * 512;
#pragma unroll
  for (int kt = 0; kt < 8; ++kt) {
    f16x8 af[2], bf[2];
#pragma unroll
    for (int mt = 0; mt < 2; ++mt) {
      const ushort* p = T1 + (mt * 16 + lm) * 264 + kt * 32 + q * 8;
      af[mt] = __builtin_bit_cast(f16x8, *(const ushort8*)p);
    }
#pragma unroll
    for (int nt = 0; nt < 2; ++nt) {
      const ushort* p = w2b + (kt * 8 + w * 2 + nt) * 512 + lane * 8;
      bf[nt] = __builtin_bit_cast(f16x8, *(const ushort8*)p);
    }
#pragma unroll
    for (int mt = 0; mt < 2; ++mt)
#pragma unroll
      for (int nt = 0; nt < 2; ++nt)
        acc2[mt][nt] = __builtin_amdgcn_mfma_f32_16x16x32_f16(af[mt], bf[nt], acc2[mt][nt], 0, 0, 0);
  }
  __syncthreads();  // T1 dead; ldsZ may now overwrite the union buffer
  float ssum[2], ssq[2];
#pragma unroll
  for (int nt = 0; nt < 2; ++nt) {
    int n = w * 32 + nt * 16 + lm;
    float bias = b2[layer * 128 + n];
    ssum[nt] = 0.f;
    ssq[nt] = 0.f;
#pragma unroll
    for (int mt = 0; mt < 2; ++mt)
#pragma unroll
      for (int r = 0; r < 4; ++r) {
        float v = acc2[mt][nt][r] + bias;
        ldsZ[(mt * 16 + q * 4 + r) * 136 + n] = f2h(v);
        ssum[nt] += v;
        ssq[nt] += v * v;
      }
    ssum[nt] += __shfl_xor(ssum[nt], 16, 64);
    ssum[nt] += __shfl_xor(ssum[nt], 32, 64);
    ssq[nt] += __shfl_xor(ssq[nt], 16, 64);
    ssq[nt] += __shfl_xor(ssq[nt], 32, 64);
  }
  if (lane < 16) {
    int cp = blockIdx.x & 15;
    float* sb = stats + (size_t)(layer * 16 + cp) * 256;
#pragma unroll
    for (int nt = 0; nt < 2; ++nt) {
      int col = w * 32 + nt * 16 + lane;
      atomicAdd(&sb[col], ssum[nt]);
      atomicAdd(&sb[128 + col], ssq[nt]);
    }
  }
  __syncthreads();
  uint* zo = (uint*)zout;
  for (int i = tid; i < 32 * 64; i += 256) {
    int row = i >> 6, cpx = i & 63;
    uint v = *(const uint*)&ldsZ[row * 136 + cpx * 2];
    zo[(size_t)(row0 + row) * 64 + cpx] = v;
  }
}

__global__ void k_bnparam(const float* __restrict__ stats, const float* __restrict__ gamma,
                          const float* __restrict__ beta, float* __restrict__ bnscale,
                          float* __restrict__ bnshift, int layer) {
  int c = threadIdx.x;
  float s = 0.f, qv = 0.f;
  for (int cp = 0; cp < 16; ++cp) {
    const float* sb = stats + (size_t)(layer * 16 + cp) * 256;
    s += sb[c];
    qv += sb[128 + c];
  }
  float mu = s * (1.0f / NN);
  float var = qv * (1.0f / NN) - mu * mu;
  float sc = gamma[layer * 128 + c] * rsqrtf(var + 1e-5f);
  bnscale[layer * 128 + c] = sc;
  bnshift[layer * 128 + c] = beta[layer * 128 + c] - mu * sc;
}

// ---------------- pooling with segmented running sum (batch sorted) ----------------
__global__ __launch_bounds__(256) void k_pool(const ushort* __restrict__ z,
                                              const float* __restrict__ bnscale,
                                              const float* __restrict__ bnshift,
                                              const int* __restrict__ batch,
                                              const float* __restrict__ Wp,
                                              float* __restrict__ out) {
  const int tid = threadIdx.x;
  const int w = tid >> 6, lane = tid & 63;
  const int nb = blockIdx.x * 64 + w * 16;
  float2 wp = ((const float2*)Wp)[lane];
  float2 scv = ((const float2*)(bnscale + 4 * 128))[lane];
  float2 shv = ((const float2*)(bnshift + 4 * 128))[lane];
  const uint* z32 = (const uint*)z;
  int bb = (lane < 16) ? batch[nb + lane] : 0;
  int curb = __shfl(bb, 0);
  float run = 0.f;
#pragma unroll
  for (int i = 0; i < 16; ++i) {
    int b = __shfl(bb, i);
    uint u = z32[(size_t)(nb + i) * 64 + lane];
    float dot = fmaf(hlo(u), scv.x, shv.x) * wp.x + fmaf(hhi(u), scv.y, shv.y) * wp.y;
#pragma unroll
    for (int off = 32; off > 0; off >>= 1) dot += __shfl_xor(dot, off, 64);
    if (b != curb) {
      if (lane == 0) atomicAdd(&out[curb], run);
      run = 0.f;
      curb = b;
    }
    run += dot;
  }
  if (lane == 0) atomicAdd(&out[curb], run);
}

extern "C" void kernel_launch(void* const* d_in, const int* in_sizes, int n_in,
                              void* d_out, int out_size, void* d_ws, size_t ws_size,
                              hipStream_t stream) {
  (void)in_sizes; (void)n_in; (void)out_size; (void)ws_size;
  const int* xidx = (const int*)d_in[0];
  const int* eidx = (const int*)d_in[1];
  const int* eattr = (const int*)d_in[2];
  const int* batch = (const int*)d_in[3];
  const float* at1 = (const float*)d_in[4];
  const float* at2 = (const float*)d_in[5];
  const float* ee1 = (const float*)d_in[6];
  const float* ee2 = (const float*)d_in[7];
  const float* W1 = (const float*)d_in[8];
  const float* b1 = (const float*)d_in[9];
  const float* W2 = (const float*)d_in[10];
  const float* b2 = (const float*)d_in[11];
  const float* gamma = (const float*)d_in[12];
  const float* beta = (const float*)d_in[13];
  const float* Wp = (const float*)d_in[14];
  const float* bp = (const float*)d_in[15];
  float* out = (float*)d_out;

  char* ws = (char*)d_ws;
  size_t off = 0;
  auto alloc = [&](size_t bytes) -> void* {
    void* p = ws + off;
    off = (off + bytes + 255) & ~(size_t)255;
    return p;
  };
  ushort* bufA = (ushort*)alloc((size_t)NN * 128 * 2);
  ushort* bufB = (ushort*)alloc((size_t)NN * 128 * 2);
  ushort* w1s = (ushort*)alloc(320 * 512 * 2);
  ushort* w2s = (ushort*)alloc(320 * 512 * 2);
  int* rowptr = (int*)alloc((NN + 1) * 4);
  int* cursor = (int*)alloc((size_t)NN * 4);
  int* eslot = (int*)alloc((size_t)EE * 4);
  int* bsums = (int*)alloc(1024 * 4);
  ushort* tabh = (ushort*)alloc(7552 * 2);
  int* xcode = (int*)alloc((size_t)NN * 4);
  float* stats = (float*)alloc((size_t)LL * 16 * 256 * 4);
  float* bnscale = (float*)alloc(LL * 128 * 4);
  float* bnshift = (float*)alloc(LL * 128 * 4);

  hipMemsetAsync(cursor, 0, (size_t)NN * 4, stream);
  hipMemsetAsync(stats, 0, (size_t)LL * 16 * 256 * 4, stream);
  k_setup<<<SCAN_NB, 256, 0, stream>>>(W1, W2, w1s, w2s, ee1, ee2, at1, at2, tabh, xidx,
                                       xcode, out, bp);
  k_count<<<(EE + 255) / 256, 256, 0, stream>>>(eidx, cursor);
  k_scanA<<<SCAN_NB, 256, 0, stream>>>(cursor, rowptr, bsums);
  k_scanB<<<1, 1024, 0, stream>>>(bsums);
  k_scanC<<<SCAN_NB, 256, 0, stream>>>(rowptr, bsums);
  hipMemcpyAsync(cursor, rowptr, (size_t)NN * 4, hipMemcpyDeviceToDevice, stream);
  k_fill<<<(EE + 255) / 256, 256, 0, stream>>>(eidx, eattr, xcode, cursor, eslot);

  for (int l = 0; l < LL; ++l) {
    ushort* zo = (l & 1) ? bufB : bufA;
    const ushort* zi = (l & 1) ? bufA : bufB;  // raw z_{l-1}; unused for l==0
    k_layer<<<NN / 32, 256, 0, stream>>>((l == 0) ? bufA : zi, zo, xcode, tabh, bnscale,
                                         bnshift, rowptr, eslot, w1s, w2s, b1, b2,
                                         stats, l);
    k_bnparam<<<1, 128, 0, stream>>>(stats, gamma, beta, bnscale, bnshift, l);
  }
  k_pool<<<NN / 64, 256, 0, stream>>>(bufA, bnscale, bnshift, batch, Wp, out);
}

// Round 19
// 571.568 us; speedup vs baseline: 1.3505x; 1.3505x over previous
//
#include <hip/hip_runtime.h>

typedef unsigned int uint;
typedef unsigned short ushort;
typedef _Float16 f16_t;
typedef f16_t f16x8 __attribute__((ext_vector_type(8)));
typedef ushort ushort8 __attribute__((ext_vector_type(8)));
typedef float f32x4 __attribute__((ext_vector_type(4)));

#define NN 200000
#define EE 600000
#define LL 5
#define GG 2000
#define SCAN_NB 782  // ceil(NN/256)

__device__ __forceinline__ ushort f2h(float f) {
  f16_t h = (f16_t)f;
  return __builtin_bit_cast(ushort, h);
}
__device__ __forceinline__ float h2f(ushort u) {
  return (float)__builtin_bit_cast(f16_t, u);
}
__device__ __forceinline__ float hlo(uint u) { return h2f((ushort)(u & 0xFFFFu)); }
__device__ __forceinline__ float hhi(uint u) { return h2f((ushort)(u >> 16)); }
__device__ __forceinline__ f16x8 ld8h(const uint4* p, int idx) {
  uint4 u = p[idx];
  return __builtin_bit_cast(f16x8, u);
}
// h = relu(z*sc+sh) in packed fp16 (v_pk_fma_f16 + v_pk_max_f16)
__device__ __forceinline__ f16x8 bnrelu8(f16x8 u, f16x8 sc, f16x8 sh) {
  f16x8 r = u * sc + sh;
#pragma unroll
  for (int j = 0; j < 8; ++j) r[j] = r[j] > (f16_t)0.f ? r[j] : (f16_t)0.f;
  return r;
}

// ---------------- merged setup: weight swizzle + fp16 tables + xcode + outinit ------
__global__ void k_setup(const float* __restrict__ W1, const float* __restrict__ W2,
                        ushort* __restrict__ w1s, ushort* __restrict__ w2s,
                        const float* __restrict__ ee1, const float* __restrict__ ee2,
                        const float* __restrict__ at1, const float* __restrict__ at2,
                        ushort* __restrict__ tabh, const int* __restrict__ xidx,
                        int* __restrict__ xcode, float* __restrict__ out,
                        const float* __restrict__ bp) {
  int i = blockIdx.x * 256 + threadIdx.x;
  if (i < 40960) {  // weight swizzle, B-frag 16x16x32 order
    int lane = i & 63;
    int f = i >> 6;
    bool isW2 = false;
    if (f >= 320) { f -= 320; isW2 = true; }
    int l = f >> 6, rem = f & 63;
    ushort8 o;
    if (!isW2) {
      int kt = rem >> 4, nt = rem & 15;
      int n = nt * 16 + (lane & 15);
      int kbase = kt * 32 + (lane >> 4) * 8;
#pragma unroll
      for (int j = 0; j < 8; ++j) o[j] = f2h(W1[l * 32768 + (kbase + j) * 256 + n]);
      *(ushort8*)(w1s + f * 512 + lane * 8) = o;
    } else {
      int kt = rem >> 3, nt = rem & 7;
      int n = nt * 16 + (lane & 15);
      int kbase = kt * 32 + (lane >> 4) * 8;
#pragma unroll
      for (int j = 0; j < 8; ++j) o[j] = f2h(W2[l * 32768 + (kbase + j) * 128 + n]);
      *(ushort8*)(w2s + f * 512 + lane * 8) = o;
    }
  }
  if (i < 5760) {  // comb (packed fp16)
    int l = i / 1152, rem = i % 1152;
    int ab = rem >> 7, c = rem & 127;
    int a = ab / 3, b = ab - a * 3;
    tabh[i] = f2h(ee1[(l * 6 + a) * 128 + c] + ee2[(l * 3 + b) * 128 + c]);
  } else if (i < 6400) {  // selfv
    int j = i - 5760;
    int l = j >> 7, c = j & 127;
    tabh[i] = f2h(ee1[(l * 6 + 4) * 128 + c] + ee2[(l * 3 + 0) * 128 + c]);
  } else if (i < 7552) {  // atomc
    int j = i - 6400;
    int ab = j >> 7, c = j & 127;
    int a = ab / 3, b = ab - a * 3;
    tabh[i] = f2h(at1[a * 128 + c] + at2[b * 128 + c]);
  }
  if (i < NN) xcode[i] = xidx[2 * i] * 3 + xidx[2 * i + 1];
  if (i < GG) out[i] = bp[0];
}

// ---------------- CSR build (dst is fixed across layers) ----------------
__global__ void k_count(const int* __restrict__ ei, int* __restrict__ counts) {
  int e = blockIdx.x * 256 + threadIdx.x;
  if (e < EE) atomicAdd(&counts[ei[EE + e]], 1);
}

__global__ void k_scanA(const int* __restrict__ counts, int* __restrict__ rowptr,
                        int* __restrict__ bsums) {
  __shared__ int sd[256];
  int tid = threadIdx.x;
  int g = blockIdx.x * 256 + tid;
  int v = (g < NN) ? counts[g] : 0;
  sd[tid] = v;
  __syncthreads();
  for (int o = 1; o < 256; o <<= 1) {
    int t = (tid >= o) ? sd[tid - o] : 0;
    __syncthreads();
    sd[tid] += t;
    __syncthreads();
  }
  if (g < NN) rowptr[g] = sd[tid] - v;
  if (tid == 255) bsums[blockIdx.x] = sd[tid];
}

__global__ void k_scanB(int* __restrict__ bsums) {
  __shared__ int sd[1024];
  int tid = threadIdx.x;
  int v = (tid < SCAN_NB) ? bsums[tid] : 0;
  sd[tid] = v;
  __syncthreads();
  for (int o = 1; o < 1024; o <<= 1) {
    int t = (tid >= o) ? sd[tid - o] : 0;
    __syncthreads();
    sd[tid] += t;
    __syncthreads();
  }
  if (tid < SCAN_NB) bsums[tid] = sd[tid] - v;
}

__global__ void k_scanC(int* __restrict__ rowptr, const int* __restrict__ bsums) {
  int g = blockIdx.x * 256 + threadIdx.x;
  if (g < NN) rowptr[g] += bsums[blockIdx.x];
  if (g == 0) rowptr[NN] = EE;
}

// pack src (18b) | a9 (4b) | xcode_src (4b)
__global__ void k_fill(const int* __restrict__ ei, const int* __restrict__ ea,
                       const int* __restrict__ xcode, int* __restrict__ cursor,
                       int* __restrict__ eslot) {
  int e = blockIdx.x * 256 + threadIdx.x;
  if (e < EE) {
    int dst = ei[EE + e];
    int src = ei[e];
    int a9 = ea[2 * e] * 3 + ea[2 * e + 1];
    int sc = xcode[src];
    int pos = atomicAdd(&cursor[dst], 1);
    eslot[pos] = src | (a9 << 18) | (sc << 22);
  }
}

// ---------------- fused layer: packed-fp16 gather (BN affine inlined), fp16 MLP ----
// Final configuration (best measured: 574-578 us total across r15/r17).
// zin holds RAW z_{l-1}; per edge: p = relu_pk(z[src]*sc+sh); acc += p + comb.
// x2 edge unroll ONLY (x4 / dual-chain spill: r8/r10/r18); no per-block fences
// (r16); BN params via 1-block k_bnparam (r10 preamble regressed).
// Block = 4 waves, 32 nodes, 16-lane sub-group per node.
// LDS: 16.9 KB union (AGG/T1/ldsZ). launch_bounds(256,5): cap above natural usage.
__global__ __launch_bounds__(256, 5) void k_layer(
    const ushort* __restrict__ zin, ushort* __restrict__ zout,
    const int* __restrict__ xcode, const ushort* __restrict__ tabh,
    const float* __restrict__ bnscale, const float* __restrict__ bnshift,
    const int* __restrict__ rowptr, const int* __restrict__ eslot,
    const ushort* __restrict__ w1s, const ushort* __restrict__ w2s,
    const float* __restrict__ b1, const float* __restrict__ b2,
    float* __restrict__ stats, int layer) {
  __shared__ __align__(16) ushort BUF[32 * 264];  // 16,896 B union
  ushort* AGG = BUF;   // 32 x 136 view (gather out / stage-1 in)
  ushort* T1 = BUF;    // 32 x 264 view (stage-1 out / stage-2 in)
  ushort* ldsZ = BUF;  // 32 x 136 view (stage-2 out / store staging)
  const int tid = threadIdx.x;
  const int w = tid >> 6, lane = tid & 63;
  const int ln16 = lane & 15, sub = lane >> 4;
  const int row0 = blockIdx.x * 32;

  // ---- gather phase: packed fp16, BN affine inlined ----
  const uint4* combH = (const uint4*)(tabh + (size_t)layer * 1152);
  const uint4* atomH = (const uint4*)(tabh + 6400);
  const uint4* selfH = (const uint4*)(tabh + 5760 + layer * 128);
  const uint4* h4 = (const uint4*)zin;
  f16x8 sf = ld8h(selfH, ln16);
  f16x8 scv = {}, shv = {};
  if (layer > 0) {
    const float* sp = bnscale + (layer - 1) * 128 + ln16 * 8;
    const float* hp = bnshift + (layer - 1) * 128 + ln16 * 8;
#pragma unroll
    for (int j = 0; j < 8; ++j) {
      scv[j] = (f16_t)sp[j];
      shv[j] = (f16_t)hp[j];
    }
  }

#pragma unroll
  for (int grp = 0; grp < 2; ++grp) {
    const int n = row0 + w * 8 + grp * 4 + sub;
    const int s = rowptr[n], e = rowptr[n + 1];
    f16x8 acc;
    if (layer == 0) {
      acc = ld8h(atomH, xcode[n] * 16 + ln16) + sf;
    } else {
      acc = bnrelu8(ld8h(h4, (size_t)n * 16 + ln16), scv, shv) + sf;
    }
    for (int base = s; base < e; base += 16) {
      int m = e - base;
      if (m > 16) m = 16;
      int slot = (ln16 < m) ? eslot[base + ln16] : 0;
      int j = 0;
      for (; j + 2 <= m; j += 2) {
        int sl0 = __shfl(slot, sub * 16 + j, 64);
        int sl1 = __shfl(slot, sub * 16 + j + 1, 64);
        f16x8 p0, p1;
        if (layer == 0) {
          p0 = ld8h(atomH, ((sl0 >> 22) & 15) * 16 + ln16);
          p1 = ld8h(atomH, ((sl1 >> 22) & 15) * 16 + ln16);
        } else {
          p0 = bnrelu8(ld8h(h4, (size_t)(sl0 & 0x3FFFF) * 16 + ln16), scv, shv);
          p1 = bnrelu8(ld8h(h4, (size_t)(sl1 & 0x3FFFF) * 16 + ln16), scv, shv);
        }
        f16x8 c0 = ld8h(combH, ((sl0 >> 18) & 15) * 16 + ln16);
        f16x8 c1 = ld8h(combH, ((sl1 >> 18) & 15) * 16 + ln16);
        acc += p0 + c0;
        acc += p1 + c1;
      }
      if (j < m) {
        int sl = __shfl(slot, sub * 16 + j, 64);
        f16x8 p0;
        if (layer == 0) {
          p0 = ld8h(atomH, ((sl >> 22) & 15) * 16 + ln16);
        } else {
          p0 = bnrelu8(ld8h(h4, (size_t)(sl & 0x3FFFF) * 16 + ln16), scv, shv);
        }
        f16x8 c0 = ld8h(combH, ((sl >> 18) & 15) * 16 + ln16);
        acc += p0 + c0;
      }
    }
    *(uint4*)&AGG[(w * 8 + grp * 4 + sub) * 136 + ln16 * 8] =
        __builtin_bit_cast(uint4, acc);
  }
  __syncthreads();

  // ---- MLP stage 1: acc = AGG @ W1, M=32, fp16; nt in pairs (smaller live set) ----
  const int lm = ln16, q = sub;
  f32x4 acc[2][4] = {};
  const ushort* w1b = w1s + layer * 64 * 512;
#pragma unroll
  for (int kt = 0; kt < 4; ++kt) {
    f16x8 af[2];
#pragma unroll
    for (int mt = 0; mt < 2; ++mt) {
      const ushort* p = AGG + (mt * 16 + lm) * 136 + kt * 32 + q * 8;
      af[mt] = __builtin_bit_cast(f16x8, *(const ushort8*)p);
    }
#pragma unroll
    for (int np = 0; np < 2; ++np) {
      f16x8 bf[2];
#pragma unroll
      for (int ni = 0; ni < 2; ++ni) {
        const ushort* p = w1b + (kt * 16 + w * 4 + np * 2 + ni) * 512 + lane * 8;
        bf[ni] = __builtin_bit_cast(f16x8, *(const ushort8*)p);
      }
#pragma unroll
      for (int mt = 0; mt < 2; ++mt)
#pragma unroll
        for (int ni = 0; ni < 2; ++ni)
          acc[mt][np * 2 + ni] = __builtin_amdgcn_mfma_f32_16x16x32_f16(
              af[mt], bf[ni], acc[mt][np * 2 + ni], 0, 0, 0);
    }
  }
  __syncthreads();  // AGG dead; T1 may now overwrite the union buffer
#pragma unroll
  for (int nt = 0; nt < 4; ++nt) {
    int n = w * 64 + nt * 16 + lm;
    float bias = b1[layer * 256 + n];
#pragma unroll
    for (int mt = 0; mt < 2; ++mt)
#pragma unroll
      for (int r = 0; r < 4; ++r) {
        float v = fmaxf(acc[mt][nt][r] + bias, 0.0f);
        T1[(mt * 16 + q * 4 + r) * 264 + n] = f2h(v);
      }
  }
  __syncthreads();

  // ---- MLP stage 2: z = T1 @ W2 + b2, + BN stats epilogue ----
  f32x4 acc2[2][2] = {};
  const ushort* w2b = w2s + layer * 64 * 512;
#pragma unroll
  for (int kt = 0; kt < 8; ++kt) {
    f16x8 af[2], bf[2];
#pragma unroll
    for (int mt = 0; mt < 2; ++mt) {
      const ushort* p = T1 + (mt * 16 + lm) * 264 + kt * 32 + q * 8;
      af[mt] = __builtin_bit_cast(f16x8, *(const ushort8*)p);
    }
#pragma unroll
    for (int nt = 0; nt < 2; ++nt) {
      const ushort* p = w2b + (kt * 8 + w * 2 + nt) * 512 + lane * 8;
      bf[nt] = __builtin_bit_cast(f16x8, *(const ushort8*)p);
    }
#pragma unroll
    for (int mt = 0; mt < 2; ++mt)
#pragma unroll
      for (int nt = 0; nt < 2; ++nt)
        acc2[mt][nt] = __builtin_amdgcn_mfma_f32_16x16x32_f16(af[mt], bf[nt], acc2[mt][nt], 0, 0, 0);
  }
  __syncthreads();  // T1 dead; ldsZ may now overwrite the union buffer
  float ssum[2], ssq[2];
#pragma unroll
  for (int nt = 0; nt < 2; ++nt) {
    int n = w * 32 + nt * 16 + lm;
    float bias = b2[layer * 128 + n];
    ssum[nt] = 0.f;
    ssq[nt] = 0.f;
#pragma unroll
    for (int mt = 0; mt < 2; ++mt)
#pragma unroll
      for (int r = 0; r < 4; ++r) {
        float v = acc2[mt][nt][r] + bias;
        ldsZ[(mt * 16 + q * 4 + r) * 136 + n] = f2h(v);
        ssum[nt] += v;
        ssq[nt] += v * v;
      }
    ssum[nt] += __shfl_xor(ssum[nt], 16, 64);
    ssum[nt] += __shfl_xor(ssum[nt], 32, 64);
    ssq[nt] += __shfl_xor(ssq[nt], 16, 64);
    ssq[nt] += __shfl_xor(ssq[nt], 32, 64);
  }
  if (lane < 16) {
    int cp = blockIdx.x & 15;
    float* sb = stats + (size_t)(layer * 16 + cp) * 256;
#pragma unroll
    for (int nt = 0; nt < 2; ++nt) {
      int col = w * 32 + nt * 16 + lane;
      atomicAdd(&sb[col], ssum[nt]);
      atomicAdd(&sb[128 + col], ssq[nt]);
    }
  }
  __syncthreads();
  uint* zo = (uint*)zout;
  for (int i = tid; i < 32 * 64; i += 256) {
    int row = i >> 6, cpx = i & 63;
    uint v = *(const uint*)&ldsZ[row * 136 + cpx * 2];
    zo[(size_t)(row0 + row) * 64 + cpx] = v;
  }
}

__global__ void k_bnparam(const float* __restrict__ stats, const float* __restrict__ gamma,
                          const float* __restrict__ beta, float* __restrict__ bnscale,
                          float* __restrict__ bnshift, int layer) {
  int c = threadIdx.x;
  float s = 0.f, qv = 0.f;
  for (int cp = 0; cp < 16; ++cp) {
    const float* sb = stats + (size_t)(layer * 16 + cp) * 256;
    s += sb[c];
    qv += sb[128 + c];
  }
  float mu = s * (1.0f / NN);
  float var = qv * (1.0f / NN) - mu * mu;
  float sc = gamma[layer * 128 + c] * rsqrtf(var + 1e-5f);
  bnscale[layer * 128 + c] = sc;
  bnshift[layer * 128 + c] = beta[layer * 128 + c] - mu * sc;
}

// ---------------- pooling with segmented running sum (batch sorted) ----------------
__global__ __launch_bounds__(256) void k_pool(const ushort* __restrict__ z,
                                              const float* __restrict__ bnscale,
                                              const float* __restrict__ bnshift,
                                              const int* __restrict__ batch,
                                              const float* __restrict__ Wp,
                                              float* __restrict__ out) {
  const int tid = threadIdx.x;
  const int w = tid >> 6, lane = tid & 63;
  const int nb = blockIdx.x * 64 + w * 16;
  float2 wp = ((const float2*)Wp)[lane];
  float2 scv = ((const float2*)(bnscale + 4 * 128))[lane];
  float2 shv = ((const float2*)(bnshift + 4 * 128))[lane];
  const uint* z32 = (const uint*)z;
  int bb = (lane < 16) ? batch[nb + lane] : 0;
  int curb = __shfl(bb, 0);
  float run = 0.f;
#pragma unroll
  for (int i = 0; i < 16; ++i) {
    int b = __shfl(bb, i);
    uint u = z32[(size_t)(nb + i) * 64 + lane];
    float dot = fmaf(hlo(u), scv.x, shv.x) * wp.x + fmaf(hhi(u), scv.y, shv.y) * wp.y;
#pragma unroll
    for (int off = 32; off > 0; off >>= 1) dot += __shfl_xor(dot, off, 64);
    if (b != curb) {
      if (lane == 0) atomicAdd(&out[curb], run);
      run = 0.f;
      curb = b;
    }
    run += dot;
  }
  if (lane == 0) atomicAdd(&out[curb], run);
}

extern "C" void kernel_launch(void* const* d_in, const int* in_sizes, int n_in,
                              void* d_out, int out_size, void* d_ws, size_t ws_size,
                              hipStream_t stream) {
  (void)in_sizes; (void)n_in; (void)out_size; (void)ws_size;
  const int* xidx = (const int*)d_in[0];
  const int* eidx = (const int*)d_in[1];
  const int* eattr = (const int*)d_in[2];
  const int* batch = (const int*)d_in[3];
  const float* at1 = (const float*)d_in[4];
  const float* at2 = (const float*)d_in[5];
  const float* ee1 = (const float*)d_in[6];
  const float* ee2 = (const float*)d_in[7];
  const float* W1 = (const float*)d_in[8];
  const float* b1 = (const float*)d_in[9];
  const float* W2 = (const float*)d_in[10];
  const float* b2 = (const float*)d_in[11];
  const float* gamma = (const float*)d_in[12];
  const float* beta = (const float*)d_in[13];
  const float* Wp = (const float*)d_in[14];
  const float* bp = (const float*)d_in[15];
  float* out = (float*)d_out;

  char* ws = (char*)d_ws;
  size_t off = 0;
  auto alloc = [&](size_t bytes) -> void* {
    void* p = ws + off;
    off = (off + bytes + 255) & ~(size_t)255;
    return p;
  };
  ushort* bufA = (ushort*)alloc((size_t)NN * 128 * 2);
  ushort* bufB = (ushort*)alloc((size_t)NN * 128 * 2);
  ushort* w1s = (ushort*)alloc(320 * 512 * 2);
  ushort* w2s = (ushort*)alloc(320 * 512 * 2);
  int* rowptr = (int*)alloc((NN + 1) * 4);
  int* cursor = (int*)alloc((size_t)NN * 4);
  int* eslot = (int*)alloc((size_t)EE * 4);
  int* bsums = (int*)alloc(1024 * 4);
  ushort* tabh = (ushort*)alloc(7552 * 2);
  int* xcode = (int*)alloc((size_t)NN * 4);
  float* stats = (float*)alloc((size_t)LL * 16 * 256 * 4);
  float* bnscale = (float*)alloc(LL * 128 * 4);
  float* bnshift = (float*)alloc(LL * 128 * 4);

  hipMemsetAsync(cursor, 0, (size_t)NN * 4, stream);
  hipMemsetAsync(stats, 0, (size_t)LL * 16 * 256 * 4, stream);
  k_setup<<<SCAN_NB, 256, 0, stream>>>(W1, W2, w1s, w2s, ee1, ee2, at1, at2, tabh, xidx,
                                       xcode, out, bp);
  k_count<<<(EE + 255) / 256, 256, 0, stream>>>(eidx, cursor);
  k_scanA<<<SCAN_NB, 256, 0, stream>>>(cursor, rowptr, bsums);
  k_scanB<<<1, 1024, 0, stream>>>(bsums);
  k_scanC<<<SCAN_NB, 256, 0, stream>>>(rowptr, bsums);
  hipMemcpyAsync(cursor, rowptr, (size_t)NN * 4, hipMemcpyDeviceToDevice, stream);
  k_fill<<<(EE + 255) / 256, 256, 0, stream>>>(eidx, eattr, xcode, cursor, eslot);

  for (int l = 0; l < LL; ++l) {
    ushort* zo = (l & 1) ? bufB : bufA;
    const ushort* zi = (l & 1) ? bufA : bufB;  // raw z_{l-1}; unused for l==0
    k_layer<<<NN / 32, 256, 0, stream>>>((l == 0) ? bufA : zi, zo, xcode, tabh, bnscale,
                                         bnshift, rowptr, eslot, w1s, w2s, b1, b2,
                                         stats, l);
    k_bnparam<<<1, 128, 0, stream>>>(stats, gamma, beta, bnscale, bnshift, l);
  }
  k_pool<<<NN / 64, 256, 0, stream>>>(bufA, bnscale, bnshift, batch, Wp, out);
}